// Round 1
// baseline (1030.328 us; speedup 1.0000x reference)
//
#include <hip/hip_runtime.h>
#include <hip/hip_bf16.h>

#define N_NODES 300000
#define N_EDGES 600000
#define IN_DIMC 64
#define HIDC    128
#define NLAYERS 2
#define BN_EPS  1e-5f
#define INV_SQRT_H 0.08838834764831845f  // 1/sqrt(128)
#define NB_SCAN ((N_NODES + 255) / 256)  // 1172
#define NTILES  (N_NODES / 16)           // 18750 (exact)
#define FUSED_GRID 2048

typedef __bf16 bf16x8 __attribute__((ext_vector_type(8)));
typedef float floatx4 __attribute__((ext_vector_type(4)));

// ---------------------------------------------------------------------------
// Module-static scratch; d_ws now holds the ping-pong h buffer (153.6 MB,
// same size as the old fp32 agg that it replaces).
// ---------------------------------------------------------------------------
__device__ int   g_row_ptr[N_NODES + 1];
__device__ int   g_cursor[N_NODES];
__device__ __align__(8) int2 g_edge[N_EDGES];   // x = src, y = bits(1/(1+len))
__device__ int   g_bsum[NB_SCAN];
__device__ float g_ekey[N_NODES];               // exp(key) per src node
__device__ __align__(16) __hip_bfloat16 g_Win_hi[128 * 64];
__device__ __align__(16) __hip_bfloat16 g_Win_lo[128 * 64];
__device__ __align__(16) __hip_bfloat16 g_Wl_hi[NLAYERS * 128 * 128];
__device__ __align__(16) __hip_bfloat16 g_Wl_lo[NLAYERS * 128 * 128];
__device__ float g_stats[NLAYERS * 2 * HIDC];   // per layer: [sum(128) | sumsq(128)]
__device__ __align__(16) float g_bn_sc[NLAYERS * HIDC];
__device__ __align__(16) float g_bn_sh[NLAYERS * HIDC];

// split fp32 into hi+lo bf16 (combined ~2^-17 relative error)
__device__ inline void split2(float x, __hip_bfloat16& hi, __hip_bfloat16& lo) {
    hi = __float2bfloat16(x);
    lo = __float2bfloat16(x - __bfloat162float(hi));
}

// ---------------------------------------------------------------------------
__global__ void zero_kernel() {
    int i = blockIdx.x * 256 + threadIdx.x;
    if (i < N_NODES) g_cursor[i] = 0;
    if (i < NLAYERS * 2 * HIDC) g_stats[i] = 0.f;
}

// ---------------------------------------------------------------------------
// Weight prep: transpose to [n][k] (MFMA B-fragments = 8 contiguous k), split.
// ---------------------------------------------------------------------------
__global__ void prep_w_kernel(const float* __restrict__ W_in,
                              const float* __restrict__ Wl)
{
    int id = blockIdx.x * 256 + threadIdx.x;
    if (id < 128 * 64) {
        int n = id >> 6, k = id & 63;
        split2(W_in[k * 128 + n], g_Win_hi[id], g_Win_lo[id]);
    }
    if (id < NLAYERS * 128 * 128) {
        int l = id >> 14, r = id & 16383;
        int n = r >> 7, k = r & 127;
        split2(Wl[l * 16384 + k * 128 + n], g_Wl_hi[id], g_Wl_lo[id]);
    }
}

// ---------------------------------------------------------------------------
// CSR build: hist -> scan -> scatter (packed src + inv-len per edge)
// ---------------------------------------------------------------------------
__global__ void hist_kernel(const int* __restrict__ dst)
{
    int e = blockIdx.x * 256 + threadIdx.x;
    if (e < N_EDGES) atomicAdd(&g_cursor[dst[e]], 1);
}

__global__ void scan1_kernel()
{
    __shared__ int tmp[256];
    int t = threadIdx.x;
    int i = blockIdx.x * 256 + t;
    tmp[t] = (i < N_NODES) ? g_cursor[i] : 0;
    __syncthreads();
    for (int d = 128; d > 0; d >>= 1) {
        if (t < d) tmp[t] += tmp[t + d];
        __syncthreads();
    }
    if (t == 0) g_bsum[blockIdx.x] = tmp[0];
}

__global__ void scan2_kernel()
{
    __shared__ int tmp[256];
    __shared__ int carry;
    int t = threadIdx.x;
    if (t == 0) { carry = 0; g_row_ptr[N_NODES] = N_EDGES; }
    __syncthreads();
    for (int base = 0; base < NB_SCAN; base += 256) {
        int i = base + t;
        int v = (i < NB_SCAN) ? g_bsum[i] : 0;
        tmp[t] = v;
        __syncthreads();
        for (int d = 1; d < 256; d <<= 1) {
            int x = (t >= d) ? tmp[t - d] : 0;
            __syncthreads();
            tmp[t] += x;
            __syncthreads();
        }
        int c = carry;
        if (i < NB_SCAN) g_bsum[i] = c + tmp[t] - v;  // exclusive
        __syncthreads();
        if (t == 0) carry = c + tmp[255];
        __syncthreads();
    }
}

__global__ void scan3_kernel()
{
    __shared__ int tmp[256];
    int t = threadIdx.x;
    int i = blockIdx.x * 256 + t;
    int v = (i < N_NODES) ? g_cursor[i] : 0;
    tmp[t] = v;
    __syncthreads();
    for (int d = 1; d < 256; d <<= 1) {
        int x = (t >= d) ? tmp[t - d] : 0;
        __syncthreads();
        tmp[t] += x;
        __syncthreads();
    }
    int r = g_bsum[blockIdx.x] + tmp[t] - v;
    if (i < N_NODES) { g_row_ptr[i] = r; g_cursor[i] = r; }
}

__global__ void scatter_kernel(const int* __restrict__ src, const int* __restrict__ dst,
                               const float* __restrict__ elen)
{
    int e = blockIdx.x * 256 + threadIdx.x;
    if (e >= N_EDGES) return;
    int d = dst[e];
    int pos = atomicAdd(&g_cursor[d], 1);
    int2 ed;
    ed.x = src[e];
    ed.y = __float_as_int(1.0f / (1.0f + elen[e]));
    g_edge[pos] = ed;
}

// ---------------------------------------------------------------------------
// proj: h[64 x 128] = X @ W_in + b via bf16x3 split MFMA; epilogue also emits
// g_ekey[n] = exp(dot(h[n], att_k) / sqrt(H)) for layer 0 (no BN before it).
// ---------------------------------------------------------------------------
__global__ __launch_bounds__(256) void proj_mfma_kernel(
    const float* __restrict__ X, const float* __restrict__ b,
    const float* __restrict__ att_k, float* __restrict__ h)
{
    __shared__ __align__(16) __hip_bfloat16 Ah[64 * 72];
    __shared__ __align__(16) __hip_bfloat16 Al[64 * 72];
    __shared__ __align__(16) __hip_bfloat16 Bh[128 * 72];
    __shared__ __align__(16) __hip_bfloat16 Bl[128 * 72];
    int t = threadIdx.x;
    int nbase = blockIdx.x * 64;

    for (int i = t; i < 1024; i += 256) {            // B: 128 rows x 64 k
        int row = i >> 3, c8 = i & 7;
        *(float4*)((char*)Bh + row * 144 + c8 * 16) =
            *(const float4*)((const char*)g_Win_hi + row * 128 + c8 * 16);
        *(float4*)((char*)Bl + row * 144 + c8 * 16) =
            *(const float4*)((const char*)g_Win_lo + row * 128 + c8 * 16);
    }
    for (int i = t; i < 1024; i += 256) {            // A: 64 rows x 64 k
        int row = i >> 4, c4 = i & 15;
        int n = nbase + row;
        float4 v = make_float4(0.f, 0.f, 0.f, 0.f);
        if (n < N_NODES) v = *(const float4*)(X + (size_t)n * IN_DIMC + c4 * 4);
        union { __hip_bfloat16 e[4]; uint2 u; } ph, pl;
        split2(v.x, ph.e[0], pl.e[0]); split2(v.y, ph.e[1], pl.e[1]);
        split2(v.z, ph.e[2], pl.e[2]); split2(v.w, ph.e[3], pl.e[3]);
        *(uint2*)((char*)Ah + row * 144 + c4 * 8) = ph.u;
        *(uint2*)((char*)Al + row * 144 + c4 * 8) = pl.u;
    }
    __syncthreads();

    int lane = t & 63, w = t >> 6;
    int m16 = lane & 15, quad = lane >> 4;
    floatx4 acc[8];
#pragma unroll
    for (int i = 0; i < 8; ++i) acc[i] = floatx4{0.f, 0.f, 0.f, 0.f};

#pragma unroll
    for (int kk = 0; kk < 64; kk += 32) {
        bf16x8 ah = *(const bf16x8*)((const char*)Ah + (w * 16 + m16) * 144 + (kk + quad * 8) * 2);
        bf16x8 al = *(const bf16x8*)((const char*)Al + (w * 16 + m16) * 144 + (kk + quad * 8) * 2);
#pragma unroll
        for (int nt = 0; nt < 8; ++nt) {
            bf16x8 bh = *(const bf16x8*)((const char*)Bh + (nt * 16 + m16) * 144 + (kk + quad * 8) * 2);
            bf16x8 bl = *(const bf16x8*)((const char*)Bl + (nt * 16 + m16) * 144 + (kk + quad * 8) * 2);
            acc[nt] = __builtin_amdgcn_mfma_f32_16x16x32_bf16(ah, bh, acc[nt], 0, 0, 0);
            acc[nt] = __builtin_amdgcn_mfma_f32_16x16x32_bf16(al, bh, acc[nt], 0, 0, 0);
            acc[nt] = __builtin_amdgcn_mfma_f32_16x16x32_bf16(ah, bl, acc[nt], 0, 0, 0);
        }
    }
    float dotr[4] = {0.f, 0.f, 0.f, 0.f};
#pragma unroll
    for (int nt = 0; nt < 8; ++nt) {
        int ch = nt * 16 + m16;
        float bias = b[ch];
        float ak = att_k[ch];
#pragma unroll
        for (int r = 0; r < 4; ++r) {
            int n = nbase + w * 16 + quad * 4 + r;
            float o = acc[nt][r] + bias;
            if (n < N_NODES) h[(size_t)n * HIDC + ch] = o;
            dotr[r] += ak * o;
        }
    }
#pragma unroll
    for (int r = 0; r < 4; ++r) {
        float p = dotr[r];
        p += __shfl_xor(p, 1); p += __shfl_xor(p, 2);
        p += __shfl_xor(p, 4); p += __shfl_xor(p, 8);
        int n = nbase + w * 16 + quad * 4 + r;
        if (m16 == 0 && n < N_NODES) g_ekey[n] = __expf(p * INV_SQRT_H);
    }
}

// ---------------------------------------------------------------------------
// key_kernel: g_ekey[n] = exp(dot(bn_prev(h[n]), att_k)/sqrt(H)).
// Half-wave (32 lanes, float4/lane) per node; 2 nodes per wave.
// ---------------------------------------------------------------------------
__global__ __launch_bounds__(256) void key_kernel(const float* __restrict__ h,
                                                  const float* __restrict__ att_k,
                                                  int prev)
{
    int t = threadIdx.x;
    int lane = t & 63;
    int half = lane >> 5, sub = lane & 31;
    int n = (blockIdx.x * 4 + (t >> 6)) * 2 + half;
    if (n >= N_NODES) return;
    float4 x = ((const float4*)h)[(size_t)n * 32 + sub];
    float4 sc = ((const float4*)(g_bn_sc + prev * HIDC))[sub];
    float4 sh = ((const float4*)(g_bn_sh + prev * HIDC))[sub];
    float4 ak = ((const float4*)att_k)[sub];
    float p = (sc.x * x.x + sh.x) * ak.x + (sc.y * x.y + sh.y) * ak.y +
              (sc.z * x.z + sh.z) * ak.z + (sc.w * x.w + sh.w) * ak.w;
    p += __shfl_xor(p, 1);  p += __shfl_xor(p, 2);
    p += __shfl_xor(p, 4);  p += __shfl_xor(p, 8);
    p += __shfl_xor(p, 16);
    if (sub == 0) g_ekey[n] = __expf(p * INV_SQRT_H);
}

// ---------------------------------------------------------------------------
// fused_layer: edge aggregation + GEMM + residual + BN-stats, no agg buffer.
//   h ping-pong: reads h_old (gather + residual), writes h_new. Per 16-node
//   tile: 8 waves x 2 nodes gather (lane = 2 channels, both nodes' chains
//   interleaved), BN-fold + relu + split2 -> bf16 hi/lo A-tile in LDS
//   (double-buffered, 17 KB); barrier; each wave MFMAs its 16-ch slice with
//   register-resident B fragments (loaded once), then residual epilogue.
// ---------------------------------------------------------------------------
__global__ __launch_bounds__(512, 4) void fused_layer_kernel(
    const float* __restrict__ h_old, float* __restrict__ h_new,
    const float* __restrict__ b, int layer, int prev)
{
    __shared__ __align__(16) __hip_bfloat16 Ah[2][16][136];
    __shared__ __align__(16) __hip_bfloat16 Al[2][16][136];

    const int t = threadIdx.x;
    const int lane = t & 63, w = t >> 6;          // w in 0..7
    const int m16 = lane & 15, quad = lane >> 4;
    const int ch = w * 16 + m16;                  // this wave's output channel

    // B fragments for this wave's 16 output channels: 2*4*16B = 64 VGPRs,
    // loaded once per block from L2-resident prepped weights.
    bf16x8 bh[4], blo[4];
    {
        const __hip_bfloat16* Wh  = g_Wl_hi + layer * 16384 + ch * 128 + quad * 8;
        const __hip_bfloat16* Wl2 = g_Wl_lo + layer * 16384 + ch * 128 + quad * 8;
#pragma unroll
        for (int kk = 0; kk < 4; ++kk) {
            bh[kk]  = *(const bf16x8*)(Wh  + kk * 32);
            blo[kk] = *(const bf16x8*)(Wl2 + kk * 32);
        }
    }

    float bias = b[ch];
    float scp = 1.f, shp = 0.f;                            // epilogue fold
    float2 scg = make_float2(1.f, 1.f), shg = make_float2(0.f, 0.f);  // gather fold
    if (prev >= 0) {
        scp = g_bn_sc[prev * HIDC + ch];
        shp = g_bn_sh[prev * HIDC + ch];
        scg = ((const float2*)(g_bn_sc + prev * HIDC))[lane];
        shg = ((const float2*)(g_bn_sh + prev * HIDC))[lane];
    }

    const float2* h2 = (const float2*)h_old;
    float sreg = 0.f, qreg = 0.f;

    // gather 2 nodes (rows w*2, w*2+1 of the tile) into A[buf]
    auto gather = [&](int tl, int buf) {
        int n0 = tl * 16 + w * 2;
        int rp0 = g_row_ptr[n0];
        int rp1 = g_row_ptr[n0 + 1];
        int rp2 = g_row_ptr[n0 + 2];
        float a0x = 0.f, a0y = 0.f, s0 = 0.f;
        float a1x = 0.f, a1y = 0.f, s1 = 0.f;
        int j0 = rp0, j1 = rp1;
        int d0 = rp1 - rp0, d1 = rp2 - rp1;
        int rmax = d0 > d1 ? d0 : d1;
        for (int r = 0; r < rmax; ++r) {          // both nodes' chains in flight
            if (j0 < rp1) {
                int2 E = g_edge[j0++];
                float wt = g_ekey[E.x] * __int_as_float(E.y);
                float2 x = h2[(size_t)E.x * 64 + lane];
                a0x += wt * x.x; a0y += wt * x.y; s0 += wt;
            }
            if (j1 < rp2) {
                int2 E = g_edge[j1++];
                float wt = g_ekey[E.x] * __int_as_float(E.y);
                float2 x = h2[(size_t)E.x * 64 + lane];
                a1x += wt * x.x; a1y += wt * x.y; s1 += wt;
            }
        }
        // BN fold (sum-of-weights trick) + relu, then split to bf16 hi/lo
        float o0x = fmaxf(scg.x * a0x + shg.x * s0, 0.f);
        float o0y = fmaxf(scg.y * a0y + shg.y * s0, 0.f);
        float o1x = fmaxf(scg.x * a1x + shg.x * s1, 0.f);
        float o1y = fmaxf(scg.y * a1y + shg.y * s1, 0.f);
        union { __hip_bfloat16 e[2]; unsigned u; } p0h, p0l, p1h, p1l;
        split2(o0x, p0h.e[0], p0l.e[0]); split2(o0y, p0h.e[1], p0l.e[1]);
        split2(o1x, p1h.e[0], p1l.e[0]); split2(o1y, p1h.e[1], p1l.e[1]);
        *(unsigned*)&Ah[buf][w * 2][2 * lane]     = p0h.u;
        *(unsigned*)&Al[buf][w * 2][2 * lane]     = p0l.u;
        *(unsigned*)&Ah[buf][w * 2 + 1][2 * lane] = p1h.u;
        *(unsigned*)&Al[buf][w * 2 + 1][2 * lane] = p1l.u;
    };

    // MFMA this wave's 16 channels over the staged tile + residual epilogue
    auto compute = [&](int tl, int buf) {
        floatx4 acc = floatx4{0.f, 0.f, 0.f, 0.f};
#pragma unroll
        for (int kk = 0; kk < 4; ++kk) {
            bf16x8 ah = *(const bf16x8*)&Ah[buf][m16][kk * 32 + quad * 8];
            bf16x8 al = *(const bf16x8*)&Al[buf][m16][kk * 32 + quad * 8];
            acc = __builtin_amdgcn_mfma_f32_16x16x32_bf16(ah, bh[kk],  acc, 0, 0, 0);
            acc = __builtin_amdgcn_mfma_f32_16x16x32_bf16(al, bh[kk],  acc, 0, 0, 0);
            acc = __builtin_amdgcn_mfma_f32_16x16x32_bf16(ah, blo[kk], acc, 0, 0, 0);
        }
        int node0 = tl * 16 + quad * 4;
#pragma unroll
        for (int r = 0; r < 4; ++r) {
            size_t off = (size_t)(node0 + r) * HIDC + ch;
            float o = scp * h_old[off] + shp + acc[r] + bias;
            h_new[off] = o;
            sreg += o; qreg += o * o;
        }
    };

    int tile = blockIdx.x;
    int cur = 0;
    gather(tile, 0);
    __syncthreads();
    for (;;) {
        int next = tile + (int)gridDim.x;
        if (next < NTILES) {
            gather(next, cur ^ 1);     // fill other buffer
            compute(tile, cur);        // consume current (synced last iter)
            __syncthreads();
            tile = next;
            cur ^= 1;
        } else {
            compute(tile, cur);
            break;
        }
    }

    // BN stats: reduce over quad (rows), lane quad==0 holds channel totals
    sreg += __shfl_xor(sreg, 16); sreg += __shfl_xor(sreg, 32);
    qreg += __shfl_xor(qreg, 16); qreg += __shfl_xor(qreg, 32);
    if (quad == 0) {
        atomicAdd(&g_stats[layer * 2 * HIDC + ch], sreg);
        atomicAdd(&g_stats[layer * 2 * HIDC + HIDC + ch], qreg);
    }
}

// ---------------------------------------------------------------------------
// bn_prep: stats -> scale/shift (1 block, 128 threads)
// ---------------------------------------------------------------------------
__global__ void bn_prep_kernel(const float* __restrict__ gamma,
                               const float* __restrict__ beta, int layer)
{
    int c = threadIdx.x;
    if (c >= HIDC) return;
    const float invN = 1.0f / (float)N_NODES;
    float mean = g_stats[layer * 2 * HIDC + c] * invN;
    float var = g_stats[layer * 2 * HIDC + HIDC + c] * invN - mean * mean;
    float s = gamma[layer * HIDC + c] * rsqrtf(var + BN_EPS);
    g_bn_sc[layer * HIDC + c] = s;
    g_bn_sh[layer * HIDC + c] = beta[layer * HIDC + c] - mean * s;
}

// ---------------------------------------------------------------------------
// bn_apply (final output only): h = sc*h + sh
// ---------------------------------------------------------------------------
__global__ __launch_bounds__(256) void bn_apply_kernel(float* __restrict__ h, int layer)
{
    size_t idx = (size_t)blockIdx.x * 256 + threadIdx.x;  // float4 index
    if (idx >= (size_t)N_NODES * (HIDC / 4)) return;
    int cg = (int)(idx & 31);
    float4 sc = ((const float4*)(g_bn_sc + layer * HIDC))[cg];
    float4 sh = ((const float4*)(g_bn_sh + layer * HIDC))[cg];
    float4 v = ((float4*)h)[idx];
    v.x = sc.x * v.x + sh.x;
    v.y = sc.y * v.y + sh.y;
    v.z = sc.z * v.z + sh.z;
    v.w = sc.w * v.w + sh.w;
    ((float4*)h)[idx] = v;
}

// ---------------------------------------------------------------------------
extern "C" void kernel_launch(void* const* d_in, const int* in_sizes, int n_in,
                              void* d_out, int out_size, void* d_ws, size_t ws_size,
                              hipStream_t stream) {
    (void)in_sizes; (void)n_in; (void)out_size; (void)ws_size;
    const float* node_init = (const float*)d_in[0];
    const int*   eidx      = (const int*)d_in[1];   // [2,E] int32
    const float* elen      = (const float*)d_in[2];
    const float* W_in      = (const float*)d_in[3];
    const float* b_in      = (const float*)d_in[4];
    const float* att_k     = (const float*)d_in[5];
    const float* Wl        = (const float*)d_in[6]; // [2,128,128]
    const float* bl        = (const float*)d_in[7]; // [2,128]
    const float* gamma     = (const float*)d_in[8];
    const float* beta      = (const float*)d_in[9];

    float* hA = (float*)d_out;  // [N,128]  (proj out, layer-1 out, final)
    float* hB = (float*)d_ws;   // [N,128]  (layer-0 out)

    const int* src = eidx;
    const int* dst = eidx + N_EDGES;

    zero_kernel<<<NB_SCAN, 256, 0, stream>>>();
    hist_kernel<<<(N_EDGES + 255) / 256, 256, 0, stream>>>(dst);
    scan1_kernel<<<NB_SCAN, 256, 0, stream>>>();
    scan2_kernel<<<1, 256, 0, stream>>>();
    scan3_kernel<<<NB_SCAN, 256, 0, stream>>>();
    scatter_kernel<<<(N_EDGES + 255) / 256, 256, 0, stream>>>(src, dst, elen);
    prep_w_kernel<<<(NLAYERS * 128 * 128 + 255) / 256, 256, 0, stream>>>(W_in, Wl);

    proj_mfma_kernel<<<(N_NODES + 63) / 64, 256, 0, stream>>>(node_init, b_in, att_k, hA);

    // layer 0: hA -> hB (ekey from proj epilogue; no BN before layer 0)
    fused_layer_kernel<<<FUSED_GRID, 512, 0, stream>>>(hA, hB, bl, 0, -1);
    bn_prep_kernel<<<1, 128, 0, stream>>>(gamma, beta, 0);

    // layer 1: hB -> hA (keys from bn0(hB))
    key_kernel<<<(N_NODES / 2 + 3) / 4, 256, 0, stream>>>(hB, att_k, 0);
    fused_layer_kernel<<<FUSED_GRID, 512, 0, stream>>>(hB, hA, bl + HIDC, 1, 0);
    bn_prep_kernel<<<1, 128, 0, stream>>>(gamma, beta, 1);

    bn_apply_kernel<<<(N_NODES * (HIDC / 4) + 255) / 256, 256, 0, stream>>>(hA, NLAYERS - 1);
}

// Round 2
// 927.502 us; speedup vs baseline: 1.1109x; 1.1109x over previous
//
#include <hip/hip_runtime.h>
#include <hip/hip_bf16.h>

#define N_NODES 300000
#define N_EDGES 600000
#define IN_DIMC 64
#define HIDC    128
#define NLAYERS 2
#define BN_EPS  1e-5f
#define INV_SQRT_H 0.08838834764831845f  // 1/sqrt(128)
#define NB_SCAN ((N_NODES + 255) / 256)  // 1172
#define NTILES  (N_NODES / 16)           // 18750 (exact)

typedef __bf16 bf16x8 __attribute__((ext_vector_type(8)));
typedef float floatx4 __attribute__((ext_vector_type(4)));

// ---------------------------------------------------------------------------
// Module-static scratch; d_ws holds only fp32 agg (153.6 MB, proven to fit).
// ---------------------------------------------------------------------------
__device__ int   g_row_ptr[N_NODES + 1];
__device__ int   g_cursor[N_NODES];
__device__ __align__(8) int2 g_edge[N_EDGES];   // x = src, y = bits(1/(1+len))
__device__ __align__(8) int2 g_ew[N_EDGES];     // per-layer: x = src, y = bits(wt)
__device__ int   g_bsum[NB_SCAN];
__device__ float g_ekey[N_NODES];               // exp(key) per src node
__device__ __align__(16) __hip_bfloat16 g_Win_hi[128 * 64];
__device__ __align__(16) __hip_bfloat16 g_Win_lo[128 * 64];
__device__ __align__(16) __hip_bfloat16 g_Wl_hi[NLAYERS * 128 * 128];
__device__ __align__(16) __hip_bfloat16 g_Wl_lo[NLAYERS * 128 * 128];
__device__ float g_stats[NLAYERS * 2 * HIDC];   // per layer: [sum(128) | sumsq(128)]
__device__ __align__(16) float g_bn_sc[NLAYERS * HIDC];
__device__ __align__(16) float g_bn_sh[NLAYERS * HIDC];

// split fp32 into hi+lo bf16 (combined ~2^-17 relative error)
__device__ inline void split2(float x, __hip_bfloat16& hi, __hip_bfloat16& lo) {
    hi = __float2bfloat16(x);
    lo = __float2bfloat16(x - __bfloat162float(hi));
}

// ---------------------------------------------------------------------------
__global__ void zero_kernel() {
    int i = blockIdx.x * 256 + threadIdx.x;
    if (i < N_NODES) g_cursor[i] = 0;
    if (i < NLAYERS * 2 * HIDC) g_stats[i] = 0.f;
}

// ---------------------------------------------------------------------------
// Weight prep: transpose to [n][k] (MFMA B-fragments = 8 contiguous k), split.
// ---------------------------------------------------------------------------
__global__ void prep_w_kernel(const float* __restrict__ W_in,
                              const float* __restrict__ Wl)
{
    int id = blockIdx.x * 256 + threadIdx.x;
    if (id < 128 * 64) {
        int n = id >> 6, k = id & 63;
        split2(W_in[k * 128 + n], g_Win_hi[id], g_Win_lo[id]);
    }
    if (id < NLAYERS * 128 * 128) {
        int l = id >> 14, r = id & 16383;
        int n = r >> 7, k = r & 127;
        split2(Wl[l * 16384 + k * 128 + n], g_Wl_hi[id], g_Wl_lo[id]);
    }
}

// ---------------------------------------------------------------------------
// CSR build: hist -> scan -> scatter (packed src + inv-len per edge)
// ---------------------------------------------------------------------------
__global__ void hist_kernel(const int* __restrict__ dst)
{
    int e = blockIdx.x * 256 + threadIdx.x;
    if (e < N_EDGES) atomicAdd(&g_cursor[dst[e]], 1);
}

__global__ void scan1_kernel()
{
    __shared__ int tmp[256];
    int t = threadIdx.x;
    int i = blockIdx.x * 256 + t;
    tmp[t] = (i < N_NODES) ? g_cursor[i] : 0;
    __syncthreads();
    for (int d = 128; d > 0; d >>= 1) {
        if (t < d) tmp[t] += tmp[t + d];
        __syncthreads();
    }
    if (t == 0) g_bsum[blockIdx.x] = tmp[0];
}

__global__ void scan2_kernel()
{
    __shared__ int tmp[256];
    __shared__ int carry;
    int t = threadIdx.x;
    if (t == 0) { carry = 0; g_row_ptr[N_NODES] = N_EDGES; }
    __syncthreads();
    for (int base = 0; base < NB_SCAN; base += 256) {
        int i = base + t;
        int v = (i < NB_SCAN) ? g_bsum[i] : 0;
        tmp[t] = v;
        __syncthreads();
        for (int d = 1; d < 256; d <<= 1) {
            int x = (t >= d) ? tmp[t - d] : 0;
            __syncthreads();
            tmp[t] += x;
            __syncthreads();
        }
        int c = carry;
        if (i < NB_SCAN) g_bsum[i] = c + tmp[t] - v;  // exclusive
        __syncthreads();
        if (t == 0) carry = c + tmp[255];
        __syncthreads();
    }
}

__global__ void scan3_kernel()
{
    __shared__ int tmp[256];
    int t = threadIdx.x;
    int i = blockIdx.x * 256 + t;
    int v = (i < N_NODES) ? g_cursor[i] : 0;
    tmp[t] = v;
    __syncthreads();
    for (int d = 1; d < 256; d <<= 1) {
        int x = (t >= d) ? tmp[t - d] : 0;
        __syncthreads();
        tmp[t] += x;
        __syncthreads();
    }
    int r = g_bsum[blockIdx.x] + tmp[t] - v;
    if (i < N_NODES) { g_row_ptr[i] = r; g_cursor[i] = r; }
}

__global__ void scatter_kernel(const int* __restrict__ src, const int* __restrict__ dst,
                               const float* __restrict__ elen)
{
    int e = blockIdx.x * 256 + threadIdx.x;
    if (e >= N_EDGES) return;
    int d = dst[e];
    int pos = atomicAdd(&g_cursor[d], 1);
    int2 ed;
    ed.x = src[e];
    ed.y = __float_as_int(1.0f / (1.0f + elen[e]));
    g_edge[pos] = ed;
}

// ---------------------------------------------------------------------------
// wt_kernel: per-layer edge weight precompute. Packs {src, wt} so edge_csr's
// inner loop is a 2-level chain (edge -> h row), no dependent ekey load.
// 600k independent threads: fully latency-hidden.
// ---------------------------------------------------------------------------
__global__ __launch_bounds__(256) void wt_kernel()
{
    int e = blockIdx.x * 256 + threadIdx.x;
    if (e >= N_EDGES) return;
    int2 ed = g_edge[e];
    int2 ew;
    ew.x = ed.x;
    ew.y = __float_as_int(g_ekey[ed.x] * __int_as_float(ed.y));
    g_ew[e] = ew;
}

// ---------------------------------------------------------------------------
// edge_csr v3: one wave per dst node; lane covers channels {2l, 2l+1}.
// Predicated 4-wide body: up to 4 independent h-row loads in flight per wave
// (deg ~ Poisson(2) -> >=96% of nodes need exactly one iteration). Dummy
// slots alias edge-0's row (L1 hit) with wt = 0. Predicates are wave-uniform.
// BN fold via sum-of-weights trick in epilogue.
// ---------------------------------------------------------------------------
__global__ __launch_bounds__(256) void edge_csr_kernel(
    const float* __restrict__ h, float* __restrict__ agg, int prev)
{
    int lane = threadIdx.x & 63;
    int n = blockIdx.x * 4 + (threadIdx.x >> 6);
    if (n >= N_NODES) return;
    int beg = g_row_ptr[n], end = g_row_ptr[n + 1];
    float a0 = 0.f, a1 = 0.f, sw = 0.f;
    const float2* h2 = (const float2*)h;
    for (int j = beg; j < end; j += 4) {
        int2 e0 = g_ew[j];
        int2 e1 = (j + 1 < end) ? g_ew[j + 1] : make_int2(e0.x, 0);
        int2 e2 = (j + 2 < end) ? g_ew[j + 2] : make_int2(e0.x, 0);
        int2 e3 = (j + 3 < end) ? g_ew[j + 3] : make_int2(e0.x, 0);
        float w0 = __int_as_float(e0.y);
        float w1 = __int_as_float(e1.y);
        float w2 = __int_as_float(e2.y);
        float w3 = __int_as_float(e3.y);
        float2 x0 = h2[(size_t)e0.x * 64 + lane];
        float2 x1 = h2[(size_t)e1.x * 64 + lane];
        float2 x2 = h2[(size_t)e2.x * 64 + lane];
        float2 x3 = h2[(size_t)e3.x * 64 + lane];
        a0 += w0 * x0.x + w1 * x1.x + w2 * x2.x + w3 * x3.x;
        a1 += w0 * x0.y + w1 * x1.y + w2 * x2.y + w3 * x3.y;
        sw += w0 + w1 + w2 + w3;
    }
    float2 sc = make_float2(1.f, 1.f), sh = make_float2(0.f, 0.f);
    if (prev >= 0) {
        sc = ((const float2*)(g_bn_sc + prev * HIDC))[lane];
        sh = ((const float2*)(g_bn_sh + prev * HIDC))[lane];
    }
    float2 o;
    o.x = fmaxf(sc.x * a0 + sh.x * sw, 0.f);
    o.y = fmaxf(sc.y * a1 + sh.y * sw, 0.f);
    ((float2*)(agg + (size_t)n * HIDC))[lane] = o;
}

// ---------------------------------------------------------------------------
// proj: h[64 x 128] = X @ W_in + b via bf16x3 split MFMA; epilogue also emits
// g_ekey[n] = exp(dot(h[n], att_k) / sqrt(H)) for layer 0 (no BN before it).
// ---------------------------------------------------------------------------
__global__ __launch_bounds__(256) void proj_mfma_kernel(
    const float* __restrict__ X, const float* __restrict__ b,
    const float* __restrict__ att_k, float* __restrict__ h)
{
    __shared__ __align__(16) __hip_bfloat16 Ah[64 * 72];
    __shared__ __align__(16) __hip_bfloat16 Al[64 * 72];
    __shared__ __align__(16) __hip_bfloat16 Bh[128 * 72];
    __shared__ __align__(16) __hip_bfloat16 Bl[128 * 72];
    int t = threadIdx.x;
    int nbase = blockIdx.x * 64;

    for (int i = t; i < 1024; i += 256) {            // B: 128 rows x 64 k
        int row = i >> 3, c8 = i & 7;
        *(float4*)((char*)Bh + row * 144 + c8 * 16) =
            *(const float4*)((const char*)g_Win_hi + row * 128 + c8 * 16);
        *(float4*)((char*)Bl + row * 144 + c8 * 16) =
            *(const float4*)((const char*)g_Win_lo + row * 128 + c8 * 16);
    }
    for (int i = t; i < 1024; i += 256) {            // A: 64 rows x 64 k
        int row = i >> 4, c4 = i & 15;
        int n = nbase + row;
        float4 v = make_float4(0.f, 0.f, 0.f, 0.f);
        if (n < N_NODES) v = *(const float4*)(X + (size_t)n * IN_DIMC + c4 * 4);
        union { __hip_bfloat16 e[4]; uint2 u; } ph, pl;
        split2(v.x, ph.e[0], pl.e[0]); split2(v.y, ph.e[1], pl.e[1]);
        split2(v.z, ph.e[2], pl.e[2]); split2(v.w, ph.e[3], pl.e[3]);
        *(uint2*)((char*)Ah + row * 144 + c4 * 8) = ph.u;
        *(uint2*)((char*)Al + row * 144 + c4 * 8) = pl.u;
    }
    __syncthreads();

    int lane = t & 63, w = t >> 6;
    int m16 = lane & 15, quad = lane >> 4;
    floatx4 acc[8];
#pragma unroll
    for (int i = 0; i < 8; ++i) acc[i] = floatx4{0.f, 0.f, 0.f, 0.f};

#pragma unroll
    for (int kk = 0; kk < 64; kk += 32) {
        bf16x8 ah = *(const bf16x8*)((const char*)Ah + (w * 16 + m16) * 144 + (kk + quad * 8) * 2);
        bf16x8 al = *(const bf16x8*)((const char*)Al + (w * 16 + m16) * 144 + (kk + quad * 8) * 2);
#pragma unroll
        for (int nt = 0; nt < 8; ++nt) {
            bf16x8 bh = *(const bf16x8*)((const char*)Bh + (nt * 16 + m16) * 144 + (kk + quad * 8) * 2);
            bf16x8 bl = *(const bf16x8*)((const char*)Bl + (nt * 16 + m16) * 144 + (kk + quad * 8) * 2);
            acc[nt] = __builtin_amdgcn_mfma_f32_16x16x32_bf16(ah, bh, acc[nt], 0, 0, 0);
            acc[nt] = __builtin_amdgcn_mfma_f32_16x16x32_bf16(al, bh, acc[nt], 0, 0, 0);
            acc[nt] = __builtin_amdgcn_mfma_f32_16x16x32_bf16(ah, bl, acc[nt], 0, 0, 0);
        }
    }
    float dotr[4] = {0.f, 0.f, 0.f, 0.f};
#pragma unroll
    for (int nt = 0; nt < 8; ++nt) {
        int ch = nt * 16 + m16;
        float bias = b[ch];
        float ak = att_k[ch];
#pragma unroll
        for (int r = 0; r < 4; ++r) {
            int n = nbase + w * 16 + quad * 4 + r;
            float o = acc[nt][r] + bias;
            if (n < N_NODES) h[(size_t)n * HIDC + ch] = o;
            dotr[r] += ak * o;
        }
    }
#pragma unroll
    for (int r = 0; r < 4; ++r) {
        float p = dotr[r];
        p += __shfl_xor(p, 1); p += __shfl_xor(p, 2);
        p += __shfl_xor(p, 4); p += __shfl_xor(p, 8);
        int n = nbase + w * 16 + quad * 4 + r;
        if (m16 == 0 && n < N_NODES) g_ekey[n] = __expf(p * INV_SQRT_H);
    }
}

// ---------------------------------------------------------------------------
// key_kernel: g_ekey[n] = exp(dot(bn_prev(h[n]), att_k)/sqrt(H)).
// Half-wave (32 lanes, float4/lane) per node; 2 nodes per wave.
// ---------------------------------------------------------------------------
__global__ __launch_bounds__(256) void key_kernel(const float* __restrict__ h,
                                                  const float* __restrict__ att_k,
                                                  int prev)
{
    int t = threadIdx.x;
    int lane = t & 63;
    int half = lane >> 5, sub = lane & 31;
    int n = (blockIdx.x * 4 + (t >> 6)) * 2 + half;
    if (n >= N_NODES) return;
    float4 x = ((const float4*)h)[(size_t)n * 32 + sub];
    float4 sc = ((const float4*)(g_bn_sc + prev * HIDC))[sub];
    float4 sh = ((const float4*)(g_bn_sh + prev * HIDC))[sub];
    float4 ak = ((const float4*)att_k)[sub];
    float p = (sc.x * x.x + sh.x) * ak.x + (sc.y * x.y + sh.y) * ak.y +
              (sc.z * x.z + sh.z) * ak.z + (sc.w * x.w + sh.w) * ak.w;
    p += __shfl_xor(p, 1);  p += __shfl_xor(p, 2);
    p += __shfl_xor(p, 4);  p += __shfl_xor(p, 8);
    p += __shfl_xor(p, 16);
    if (sub == 0) g_ekey[n] = __expf(p * INV_SQRT_H);
}

// ---------------------------------------------------------------------------
// layer_gemm: stage B (hi+lo) once; waves grid-stride over 16-node tiles,
// A fragments straight from global. Epilogue applies bn_prev to residual,
// accumulates BN stats in registers.
// ---------------------------------------------------------------------------
__global__ __launch_bounds__(256) void layer_gemm_kernel(
    float* __restrict__ h, const float* __restrict__ agg,
    const float* __restrict__ b, int layer, int prev)
{
    __shared__ __align__(16) __hip_bfloat16 Bh[128 * 136];
    __shared__ __align__(16) __hip_bfloat16 Bl[128 * 136];
    __shared__ float red[256];
    int t = threadIdx.x;
    const __hip_bfloat16* Wh = g_Wl_hi + layer * 16384;
    const __hip_bfloat16* Wlo = g_Wl_lo + layer * 16384;
    red[t] = 0.f;

    for (int i = t; i < 2048; i += 256) {      // B: [n=128][k=128], stride 272B
        int row = i >> 4, c8 = i & 15;
        *(float4*)((char*)Bh + row * 272 + c8 * 16) =
            *(const float4*)((const char*)Wh + row * 256 + c8 * 16);
        *(float4*)((char*)Bl + row * 272 + c8 * 16) =
            *(const float4*)((const char*)Wlo + row * 256 + c8 * 16);
    }
    __syncthreads();

    const int lane = t & 63, w = t >> 6;
    const int m16 = lane & 15, quad = lane >> 4;
    const int wid = blockIdx.x * 4 + w;
    const int nwaves = gridDim.x * 4;

    float bias[8], scp[8], shp[8];
#pragma unroll
    for (int nt = 0; nt < 8; ++nt) {
        int ch = nt * 16 + m16;
        bias[nt] = b[ch];
        scp[nt] = (prev >= 0) ? g_bn_sc[prev * HIDC + ch] : 1.f;
        shp[nt] = (prev >= 0) ? g_bn_sh[prev * HIDC + ch] : 0.f;
    }
    float sreg[8], qreg[8];
#pragma unroll
    for (int nt = 0; nt < 8; ++nt) { sreg[nt] = 0.f; qreg[nt] = 0.f; }

    for (int tile = wid; tile < NTILES; tile += nwaves) {
        const float* arow = agg + (size_t)(tile * 16 + m16) * HIDC + quad * 8;
        floatx4 acc[8];
#pragma unroll
        for (int i = 0; i < 8; ++i) acc[i] = floatx4{0.f, 0.f, 0.f, 0.f};

#pragma unroll
        for (int kk = 0; kk < 4; ++kk) {
            float4 a0 = *(const float4*)(arow + kk * 32);
            float4 a1 = *(const float4*)(arow + kk * 32 + 4);
            union { __hip_bfloat16 e[8]; bf16x8 v; } ah, al;
            split2(a0.x, ah.e[0], al.e[0]); split2(a0.y, ah.e[1], al.e[1]);
            split2(a0.z, ah.e[2], al.e[2]); split2(a0.w, ah.e[3], al.e[3]);
            split2(a1.x, ah.e[4], al.e[4]); split2(a1.y, ah.e[5], al.e[5]);
            split2(a1.z, ah.e[6], al.e[6]); split2(a1.w, ah.e[7], al.e[7]);
#pragma unroll
            for (int nt = 0; nt < 8; ++nt) {
                bf16x8 bh = *(const bf16x8*)((const char*)Bh + (nt * 16 + m16) * 272 + (kk * 32 + quad * 8) * 2);
                bf16x8 bl = *(const bf16x8*)((const char*)Bl + (nt * 16 + m16) * 272 + (kk * 32 + quad * 8) * 2);
                acc[nt] = __builtin_amdgcn_mfma_f32_16x16x32_bf16(ah.v, bh, acc[nt], 0, 0, 0);
                acc[nt] = __builtin_amdgcn_mfma_f32_16x16x32_bf16(al.v, bh, acc[nt], 0, 0, 0);
                acc[nt] = __builtin_amdgcn_mfma_f32_16x16x32_bf16(ah.v, bl, acc[nt], 0, 0, 0);
            }
        }
        int node0 = tile * 16 + quad * 4;
#pragma unroll
        for (int nt = 0; nt < 8; ++nt) {
            int ch = nt * 16 + m16;
#pragma unroll
            for (int r = 0; r < 4; ++r) {
                float* hp = h + (size_t)(node0 + r) * HIDC + ch;
                float o = scp[nt] * (*hp) + shp[nt] + acc[nt][r] + bias[nt];
                *hp = o;
                sreg[nt] += o;
                qreg[nt] += o * o;
            }
        }
    }

#pragma unroll
    for (int nt = 0; nt < 8; ++nt) {
        float s = sreg[nt], q = qreg[nt];
        s += __shfl_xor(s, 16); s += __shfl_xor(s, 32);
        q += __shfl_xor(q, 16); q += __shfl_xor(q, 32);
        if (quad == 0) {
            atomicAdd(&red[nt * 16 + m16], s);
            atomicAdd(&red[HIDC + nt * 16 + m16], q);
        }
    }
    __syncthreads();
    atomicAdd(&g_stats[layer * 2 * HIDC + t], red[t]);
}

// ---------------------------------------------------------------------------
// bn_prep: stats -> scale/shift (1 block, 128 threads)
// ---------------------------------------------------------------------------
__global__ void bn_prep_kernel(const float* __restrict__ gamma,
                               const float* __restrict__ beta, int layer)
{
    int c = threadIdx.x;
    if (c >= HIDC) return;
    const float invN = 1.0f / (float)N_NODES;
    float mean = g_stats[layer * 2 * HIDC + c] * invN;
    float var = g_stats[layer * 2 * HIDC + HIDC + c] * invN - mean * mean;
    float s = gamma[layer * HIDC + c] * rsqrtf(var + BN_EPS);
    g_bn_sc[layer * HIDC + c] = s;
    g_bn_sh[layer * HIDC + c] = beta[layer * HIDC + c] - mean * s;
}

// ---------------------------------------------------------------------------
// bn_apply (final output only): h = sc*h + sh
// ---------------------------------------------------------------------------
__global__ __launch_bounds__(256) void bn_apply_kernel(float* __restrict__ h, int layer)
{
    size_t idx = (size_t)blockIdx.x * 256 + threadIdx.x;  // float4 index
    if (idx >= (size_t)N_NODES * (HIDC / 4)) return;
    int cg = (int)(idx & 31);
    float4 sc = ((const float4*)(g_bn_sc + layer * HIDC))[cg];
    float4 sh = ((const float4*)(g_bn_sh + layer * HIDC))[cg];
    float4 v = ((float4*)h)[idx];
    v.x = sc.x * v.x + sh.x;
    v.y = sc.y * v.y + sh.y;
    v.z = sc.z * v.z + sh.z;
    v.w = sc.w * v.w + sh.w;
    ((float4*)h)[idx] = v;
}

// ---------------------------------------------------------------------------
extern "C" void kernel_launch(void* const* d_in, const int* in_sizes, int n_in,
                              void* d_out, int out_size, void* d_ws, size_t ws_size,
                              hipStream_t stream) {
    (void)in_sizes; (void)n_in; (void)out_size; (void)ws_size;
    const float* node_init = (const float*)d_in[0];
    const int*   eidx      = (const int*)d_in[1];   // [2,E] int32
    const float* elen      = (const float*)d_in[2];
    const float* W_in      = (const float*)d_in[3];
    const float* b_in      = (const float*)d_in[4];
    const float* att_k     = (const float*)d_in[5];
    const float* Wl        = (const float*)d_in[6]; // [2,128,128]
    const float* bl        = (const float*)d_in[7]; // [2,128]
    const float* gamma     = (const float*)d_in[8];
    const float* beta      = (const float*)d_in[9];

    float* h   = (float*)d_out;  // [N,128]
    float* agg = (float*)d_ws;   // [N,128] fp32

    const int* src = eidx;
    const int* dst = eidx + N_EDGES;

    zero_kernel<<<NB_SCAN, 256, 0, stream>>>();
    hist_kernel<<<(N_EDGES + 255) / 256, 256, 0, stream>>>(dst);
    scan1_kernel<<<NB_SCAN, 256, 0, stream>>>();
    scan2_kernel<<<1, 256, 0, stream>>>();
    scan3_kernel<<<NB_SCAN, 256, 0, stream>>>();
    scatter_kernel<<<(N_EDGES + 255) / 256, 256, 0, stream>>>(src, dst, elen);
    prep_w_kernel<<<(NLAYERS * 128 * 128 + 255) / 256, 256, 0, stream>>>(W_in, Wl);

    proj_mfma_kernel<<<(N_NODES + 63) / 64, 256, 0, stream>>>(node_init, b_in, att_k, h);

    for (int l = 0; l < NLAYERS; ++l) {
        if (l > 0)
            key_kernel<<<(N_NODES / 2 + 3) / 4, 256, 0, stream>>>(h, att_k, l - 1);
        wt_kernel<<<(N_EDGES + 255) / 256, 256, 0, stream>>>();
        edge_csr_kernel<<<(N_NODES + 3) / 4, 256, 0, stream>>>(h, agg, l - 1);
        layer_gemm_kernel<<<512, 256, 0, stream>>>(h, agg, bl + (size_t)l * HIDC, l, l - 1);
        bn_prep_kernel<<<1, 128, 0, stream>>>(gamma, beta, l);
    }
    bn_apply_kernel<<<(N_NODES * (HIDC / 4) + 255) / 256, 256, 0, stream>>>(h, NLAYERS - 1);
}